// Round 1
// baseline (1290.222 us; speedup 1.0000x reference)
//
#include <hip/hip_runtime.h>

typedef unsigned short u16;
typedef short short8 __attribute__((ext_vector_type(8)));
typedef float f32x4 __attribute__((ext_vector_type(4)));
typedef unsigned short u16x4 __attribute__((ext_vector_type(4)));

#define CDIM 768
#define NP 1024
#define NB 32

static constexpr size_t CHW = (size_t)NB * CDIM * NP;  // 25,165,824 elements

// workspace layout (bytes)
static constexpr size_t XT_HI_OFF = 0;                        // bf16 [b][p][c]
static constexpr size_t XT_LO_OFF = CHW * 2;                  // 50,331,648
static constexpr size_t W_HI_OFF  = CHW * 4;                  // 100,663,296
static constexpr size_t W_LO_OFF  = W_HI_OFF + (size_t)9 * CDIM * CDIM * 2;
static constexpr size_t HS_OFF    = W_LO_OFF + (size_t)9 * CDIM * CDIM * 2;  // hs11, hs111 fp32
static constexpr size_t ATTOUT_OFF = 0;                       // fp32, aliases XT (XT dead by then)
static constexpr size_t AOT_HI_OFF = HS_OFF;                  // aliases hs (hs dead by then)
static constexpr size_t AOT_LO_OFF = HS_OFF + CHW * 2;

__device__ __forceinline__ u16 bf16rn(float f) {
  unsigned u = __float_as_uint(f);
  u += 0x7fffu + ((u >> 16) & 1u);
  return (u16)(u >> 16);
}

typedef __attribute__((address_space(1))) void gv_t;
typedef __attribute__((address_space(3))) void lv_t;
__device__ __forceinline__ void gload_lds16(const void* g, void* l) {
  __builtin_amdgcn_global_load_lds((gv_t*)g, (lv_t*)l, 16, 0, 0);
}

// ---------------- split W (fp32 -> bf16 hi/lo) ----------------
__global__ __launch_bounds__(256) void split_w_k(const float* __restrict__ W,
                                                 u16* __restrict__ hi, u16* __restrict__ lo) {
  int i = blockIdx.x * 256 + threadIdx.x;  // float4 index; grid sized exactly
  float4 v = ((const float4*)W)[i];
  float f[4] = {v.x, v.y, v.z, v.w};
  u16 hh[4], ll[4];
#pragma unroll
  for (int e = 0; e < 4; ++e) {
    hh[e] = bf16rn(f[e]);
    float fh = __uint_as_float((unsigned)hh[e] << 16);
    ll[e] = bf16rn(f[e] - fh);
  }
  u16x4 h4 = {hh[0], hh[1], hh[2], hh[3]};
  u16x4 l4v = {ll[0], ll[1], ll[2], ll[3]};
  ((u16x4*)hi)[i] = h4;
  ((u16x4*)lo)[i] = l4v;
}

// ---------------- transpose + split: src fp32 [b][c][p] -> dst bf16 [b][p][c] ----------------
__global__ __launch_bounds__(256) void transpose_split_k(const float* __restrict__ src,
                                                         u16* __restrict__ dhi, u16* __restrict__ dlo) {
  __shared__ float tle[32][33];
  const int b = blockIdx.z, c0 = blockIdx.y * 32, p0 = blockIdx.x * 32;
  const int tid = threadIdx.x;
  const int lr = tid >> 5, lc = tid & 31;
  const float* s = src + ((size_t)b * CDIM + c0) * NP + p0;
#pragma unroll
  for (int it = 0; it < 4; ++it) {
    int c = it * 8 + lr;
    tle[c][lc] = s[(size_t)c * NP + lc];
  }
  __syncthreads();
#pragma unroll
  for (int it = 0; it < 4; ++it) {
    int p = it * 8 + lr;
    float v = tle[lc][p];
    u16 h = bf16rn(v);
    float fh = __uint_as_float((unsigned)h << 16);
    u16 l = bf16rn(v - fh);
    size_t off = ((size_t)b * NP + p0 + p) * CDIM + c0 + lc;
    dhi[off] = h;
    dlo[off] = l;
  }
}

// ---------------- spatial permutations ----------------
// mode 0 = stage1 (z selects hs11/hs111 group), mode 1 = identity
__device__ __forceinline__ int sigma_fn(int mode, int z, int t, int p) {
  if (t == 0 || mode == 1) return p;
  int i = p >> 5, j = p & 31;
  if (z == 0) {
    if (t == 1) return (j << 5) | (31 - i);
    if (t == 2) return ((31 - i) << 5) | (31 - j);
    return ((31 - j) << 5) | i;
  } else {
    int ib = i & 16, jb = j & 16, il = i & 15, jl = j & 15;
    if (t == 1) return ((ib | jl) << 5) | (jb | (15 - il));
    if (t == 2) return ((ib | (15 - il)) << 5) | (jb | (15 - jl));
    return ((ib | (15 - jl)) << 5) | (jb | il);
  }
}

// ---------------- multi-term split-bf16 GEMM with permuted column gather ----------------
// dst[z][b][o][p] = sum_t relu( W[wselBase+4z+t] @ X[:, sigma(p)] + bias )
// A (W) layout [mat][o][c] bf16 hi/lo; B (X) layout [b][p][c] bf16 hi/lo.
__global__ __launch_bounds__(256, 2) void gemm_ms(
    const u16* __restrict__ Whi, const u16* __restrict__ Wlo,
    const u16* __restrict__ Bhi, const u16* __restrict__ Blo,
    const float* __restrict__ bias, float* __restrict__ dst,
    int nterms, int wselBase, int mode) {
  __shared__ u16 lds[16384];  // A: [0,8192) u16 (16KB), B: [8192,16384)
  const int tid = threadIdx.x;
  const int lane = tid & 63;
  const int w = tid >> 6;
  const int wr = w >> 1, wc = w & 1;
  const int z = blockIdx.z;
  const int b = blockIdx.x >> 3;
  const int p0 = (blockIdx.x & 7) << 7;
  const int o0 = blockIdx.y << 7;
  const int l15 = lane & 15, l4 = lane >> 4;

  float* dstz = dst + (size_t)z * CHW;

  // per-thread staging decode: slot d -> row=d>>3, stored-chunk c3 with XOR swizzle
  int rowA[4], c3A[4];
#pragma unroll
  for (int it = 0; it < 4; ++it) {
    int d = it * 256 + tid;
    rowA[it] = d >> 3;
    c3A[it] = (d & 7) ^ (rowA[it] & 7);
  }

  f32x4 racc[4][4];
#pragma unroll
  for (int m = 0; m < 4; ++m)
#pragma unroll
    for (int n = 0; n < 4; ++n) racc[m][n] = (f32x4){0.f, 0.f, 0.f, 0.f};

  for (int t = 0; t < nterms; ++t) {
    const int wsel = wselBase + z * 4 + t;
    const u16* aptr[4];
    const u16* bptr[4];
#pragma unroll
    for (int it = 0; it < 4; ++it) {
      int c3 = c3A[it];
      const u16* wb = (c3 & 4) ? Wlo : Whi;
      aptr[it] = wb + ((size_t)wsel * CDIM + o0 + rowA[it]) * CDIM + (c3 & 3) * 8;
      int srow = sigma_fn(mode, z, t, p0 + rowA[it]);
      const u16* xb = (c3 & 4) ? Blo : Bhi;
      bptr[it] = xb + ((size_t)b * NP + srow) * CDIM + (c3 & 3) * 8;
    }
    f32x4 acc[4][4];
#pragma unroll
    for (int m = 0; m < 4; ++m)
#pragma unroll
      for (int n = 0; n < 4; ++n) acc[m][n] = (f32x4){0.f, 0.f, 0.f, 0.f};

    for (int k0 = 0; k0 < CDIM; k0 += 32) {
      __syncthreads();  // prior ds_reads done before overwrite
#pragma unroll
      for (int it = 0; it < 4; ++it)
        gload_lds16(aptr[it] + k0, &lds[(size_t)(it * 256 + (w << 6)) * 8]);
#pragma unroll
      for (int it = 0; it < 4; ++it)
        gload_lds16(bptr[it] + k0, &lds[8192 + (size_t)(it * 256 + (w << 6)) * 8]);
      __syncthreads();  // drains vmcnt(0) before barrier

      short8 ah[4], al[4], bh[4], bl[4];
#pragma unroll
      for (int m = 0; m < 4; ++m) {
        int row = wr * 64 + m * 16 + l15;
        ah[m] = *(const short8*)&lds[(row * 8 + (l4 ^ (row & 7))) * 8];
        al[m] = *(const short8*)&lds[(row * 8 + ((4 + l4) ^ (row & 7))) * 8];
      }
#pragma unroll
      for (int n = 0; n < 4; ++n) {
        int col = wc * 64 + n * 16 + l15;
        bh[n] = *(const short8*)&lds[8192 + (col * 8 + (l4 ^ (col & 7))) * 8];
        bl[n] = *(const short8*)&lds[8192 + (col * 8 + ((4 + l4) ^ (col & 7))) * 8];
      }
#pragma unroll
      for (int m = 0; m < 4; ++m)
#pragma unroll
        for (int n = 0; n < 4; ++n) {
          acc[m][n] = __builtin_amdgcn_mfma_f32_16x16x32_bf16(ah[m], bh[n], acc[m][n], 0, 0, 0);
          acc[m][n] = __builtin_amdgcn_mfma_f32_16x16x32_bf16(ah[m], bl[n], acc[m][n], 0, 0, 0);
          acc[m][n] = __builtin_amdgcn_mfma_f32_16x16x32_bf16(al[m], bh[n], acc[m][n], 0, 0, 0);
        }
    }
    // relu(term + bias) accumulation
#pragma unroll
    for (int m = 0; m < 4; ++m) {
      float4 bv = *(const float4*)&bias[wsel * CDIM + o0 + wr * 64 + m * 16 + l4 * 4];
      float bvf[4] = {bv.x, bv.y, bv.z, bv.w};
#pragma unroll
      for (int n = 0; n < 4; ++n)
#pragma unroll
        for (int r = 0; r < 4; ++r) racc[m][n][r] += fmaxf(0.f, acc[m][n][r] + bvf[r]);
    }
  }
  // C write: row = o0+wr*64+m*16+l4*4+r, col = p0+wc*64+n*16+l15
#pragma unroll
  for (int m = 0; m < 4; ++m) {
    int rowb = o0 + wr * 64 + m * 16 + l4 * 4;
#pragma unroll
    for (int n = 0; n < 4; ++n) {
      int col = p0 + wc * 64 + n * 16 + l15;
      float* dp = dstz + ((size_t)b * CDIM + rowb) * NP + col;
#pragma unroll
      for (int r = 0; r < 4; ++r) dp[(size_t)r * NP] = racc[m][n][r];
    }
  }
}

// ---------------- per-(b,c) 32x32 attention, fp32, one wave per pair ----------------
__global__ __launch_bounds__(256) void attn_k(const float* __restrict__ hs, float* __restrict__ aout) {
  __shared__ float q[4][1056];   // pitch 33
  __shared__ float kk[4][1056];
  const int tid = threadIdx.x, w = tid >> 6, lane = tid & 63;
  const int pair0 = blockIdx.x * 4;
#pragma unroll
  for (int it = 0; it < 8; ++it) {
    int d4 = it * 256 + tid;
    int pr = d4 >> 9;
    int mat = (d4 >> 8) & 1;
    int off4 = d4 & 255;
    float4 v = *(const float4*)&hs[(size_t)mat * CHW + (size_t)(pair0 + pr) * NP + off4 * 4];
    float* dl = mat ? kk[pr] : q[pr];
    int off = off4 * 4;
    int base = (off >> 5) * 33 + (off & 31);
    dl[base] = v.x; dl[base + 1] = v.y; dl[base + 2] = v.z; dl[base + 3] = v.w;
  }
  __syncthreads();
  const int i = lane & 31, half = lane >> 5, jb = half * 16;
  const float* Q = q[w];
  const float* K = kk[w];
  float qr[32];
#pragma unroll
  for (int tt = 0; tt < 32; ++tt) qr[tt] = Q[i * 33 + tt];
  float a[16];
#pragma unroll
  for (int j = 0; j < 16; ++j) {
    float s = 0.f;
#pragma unroll
    for (int tt = 0; tt < 32; ++tt) s = fmaf(qr[tt], K[tt * 33 + jb + j], s);
    a[j] = s;
  }
  float mx = a[0];
#pragma unroll
  for (int j = 1; j < 16; ++j) mx = fmaxf(mx, a[j]);
  mx = fmaxf(mx, __shfl_xor(mx, 32));
  float ssum = 0.f;
#pragma unroll
  for (int j = 0; j < 16; ++j) { a[j] = expf(a[j] - mx); ssum += a[j]; }
  ssum += __shfl_xor(ssum, 32);
  float inv = 1.f / ssum;
#pragma unroll
  for (int j = 0; j < 16; ++j) a[j] *= inv;
  // out[i][h] = sum_j p[i][j] * v[j][h]; v == q buffer. Stage result into kk (K is dead).
#pragma unroll
  for (int h = 0; h < 32; ++h) {
    float o = 0.f;
#pragma unroll
    for (int j = 0; j < 16; ++j) o = fmaf(a[j], Q[(jb + j) * 33 + h], o);
    o += __shfl_xor(o, 32);
    if (half == (h >> 4)) kk[w][i * 33 + h] = o;
  }
  __syncthreads();
#pragma unroll
  for (int it = 0; it < 4; ++it) {
    int d4 = it * 256 + tid;
    int pr = d4 >> 8, off4 = d4 & 255, off = off4 * 4;
    int base = (off >> 5) * 33 + (off & 31);
    const float* sl = kk[pr];
    float4 v = {sl[base], sl[base + 1], sl[base + 2], sl[base + 3]};
    *(float4*)&aout[(size_t)(pair0 + pr) * NP + off] = v;
  }
}

extern "C" void kernel_launch(void* const* d_in, const int* in_sizes, int n_in,
                              void* d_out, int out_size, void* d_ws, size_t ws_size,
                              hipStream_t stream) {
  (void)in_sizes; (void)n_in; (void)out_size; (void)ws_size;
  const float* x = (const float*)d_in[0];
  const float* Ws = (const float*)d_in[1];
  const float* bs = (const float*)d_in[2];
  float* out = (float*)d_out;
  char* ws = (char*)d_ws;

  u16* XThi = (u16*)(ws + XT_HI_OFF);
  u16* XTlo = (u16*)(ws + XT_LO_OFF);
  u16* Whi = (u16*)(ws + W_HI_OFF);
  u16* Wlo = (u16*)(ws + W_LO_OFF);
  float* hs = (float*)(ws + HS_OFF);           // hs11 then hs111
  float* attout = (float*)(ws + ATTOUT_OFF);   // aliases XT
  u16* aoThi = (u16*)(ws + AOT_HI_OFF);        // aliases hs
  u16* aoTlo = (u16*)(ws + AOT_LO_OFF);

  // 1. split weights: 9*768*768/4 = 1,327,104 float4 -> 5184 blocks * 256
  split_w_k<<<5184, 256, 0, stream>>>(Ws, Whi, Wlo);
  // 2. x [b][c][p] -> XT bf16 hi/lo [b][p][c]
  transpose_split_k<<<dim3(32, 24, 32), 256, 0, stream>>>(x, XThi, XTlo);
  // 3. stage-1: hs11 (z=0, W0..3) and hs111 (z=1, W4..7)
  gemm_ms<<<dim3(256, 6, 2), 256, 0, stream>>>(Whi, Wlo, XThi, XTlo, bs, hs, 4, 0, 0);
  // 4. attention per (b,c): q=v=hs11, k=hs111 -> attout [b][c][p]
  attn_k<<<6144, 256, 0, stream>>>(hs, attout);
  // 5. attout -> aoT bf16 hi/lo [b][p][c]
  transpose_split_k<<<dim3(32, 24, 32), 256, 0, stream>>>(attout, aoThi, aoTlo);
  // 6. final conv: relu(W8 @ attout + b8) -> d_out
  gemm_ms<<<dim3(256, 6, 1), 256, 0, stream>>>(Whi, Wlo, aoThi, aoTlo, bs, out, 1, 8, 1);
}

// Round 2
// 992.962 us; speedup vs baseline: 1.2994x; 1.2994x over previous
//
#include <hip/hip_runtime.h>
#include <hip/hip_fp16.h>

typedef unsigned short u16;
typedef float f32x4 __attribute__((ext_vector_type(4)));
typedef _Float16 half8 __attribute__((ext_vector_type(8)));
typedef unsigned short u16x4 __attribute__((ext_vector_type(4)));

#define CDIM 768
#define NP 1024
#define NB 32

static constexpr size_t CHW = (size_t)NB * CDIM * NP;  // 25,165,824

// workspace layout (bytes)
static constexpr size_t XT_OFF  = 0;                         // f16 [b][p][c]; later reused as aoT f16
static constexpr size_t HS_OFF  = CHW * 2;                   // fp32 hs11, hs111 (2*CHW*4)
static constexpr size_t WHI_OFF = HS_OFF + CHW * 8;          // f16 hi
static constexpr size_t WLO_OFF = WHI_OFF + (size_t)9 * CDIM * CDIM * 2;
// end = WLO_OFF + 10.6MB ~= 273 MB (< previous proven 322 MB usage)

__device__ __forceinline__ u16 f16bits(float f) {
  return __half_as_ushort(__float2half_rn(f));
}

typedef __attribute__((address_space(1))) void gv_t;
typedef __attribute__((address_space(3))) void lv_t;
__device__ __forceinline__ void gload_lds16(const void* g, void* l) {
  __builtin_amdgcn_global_load_lds((gv_t*)g, (lv_t*)l, 16, 0, 0);
}

// ---------------- split W (fp32 -> f16 hi + f16 lo) ----------------
__global__ __launch_bounds__(256) void split_w_k(const float* __restrict__ W,
                                                 u16* __restrict__ hi, u16* __restrict__ lo) {
  int i = blockIdx.x * 256 + threadIdx.x;  // float4 index; grid sized exactly
  float4 v = ((const float4*)W)[i];
  float f[4] = {v.x, v.y, v.z, v.w};
  u16 hh[4], ll[4];
#pragma unroll
  for (int e = 0; e < 4; ++e) {
    __half h = __float2half_rn(f[e]);
    hh[e] = __half_as_ushort(h);
    ll[e] = f16bits(f[e] - __half2float(h));
  }
  u16x4 h4 = {hh[0], hh[1], hh[2], hh[3]};
  u16x4 l4v = {ll[0], ll[1], ll[2], ll[3]};
  ((u16x4*)hi)[i] = h4;
  ((u16x4*)lo)[i] = l4v;
}

// ---------------- transpose + f16 cast: src fp32 [b][c][p] -> dst f16 [b][p][c] ----------------
__global__ __launch_bounds__(256) void transpose_f16_k(const float* __restrict__ src,
                                                       u16* __restrict__ dxt) {
  __shared__ float tle[32][33];
  const int b = blockIdx.z, c0 = blockIdx.y * 32, p0 = blockIdx.x * 32;
  const int tid = threadIdx.x;
  const int lr = tid >> 5, lc = tid & 31;
  const float* s = src + ((size_t)b * CDIM + c0) * NP + p0;
#pragma unroll
  for (int it = 0; it < 4; ++it) {
    int c = it * 8 + lr;
    tle[c][lc] = s[(size_t)c * NP + lc];
  }
  __syncthreads();
#pragma unroll
  for (int it = 0; it < 4; ++it) {
    int p = it * 8 + lr;
    float v = tle[lc][p];
    size_t off = ((size_t)b * NP + p0 + p) * CDIM + c0 + lc;
    dxt[off] = f16bits(v);
  }
}

// ---------------- spatial permutations ----------------
__device__ __forceinline__ int sigma_fn(int mode, int z, int t, int p) {
  if (t == 0 || mode == 1) return p;
  int i = p >> 5, j = p & 31;
  if (z == 0) {
    if (t == 1) return (j << 5) | (31 - i);
    if (t == 2) return ((31 - i) << 5) | (31 - j);
    return ((31 - j) << 5) | i;
  } else {
    int ib = i & 16, jb = j & 16, il = i & 15, jl = j & 15;
    if (t == 1) return ((ib | jl) << 5) | (jb | (15 - il));
    if (t == 2) return ((ib | (15 - il)) << 5) | (jb | (15 - jl));
    return ((ib | (15 - jl)) << 5) | (jb | il);
  }
}

// ---------------- multi-term 2x-f16-split GEMM with permuted column gather ----------------
// dst[z][b][o][p] = sum_t relu( (Whi+Wlo)[wsel] @ Xf16[:, sigma(p)] + bias )
// A (W) layout [mat][o][c] f16 hi/lo; B (X) layout [b][p][c] f16.
__global__ __launch_bounds__(256, 2) void gemm_ms(
    const u16* __restrict__ Whi, const u16* __restrict__ Wlo,
    const u16* __restrict__ Bx,
    const float* __restrict__ bias, float* __restrict__ dst,
    int nterms, int wselBase, int mode) {
  __shared__ u16 lds[12288];  // A: [0,8192) = 128 rows x 64 (hi cols 0-31 | lo cols 32-63); B: [8192,12288) = 128 x 32
  const int tid = threadIdx.x;
  const int lane = tid & 63;
  const int w = tid >> 6;
  const int wr = w >> 1, wc = w & 1;
  const int z = blockIdx.z;
  const int b = blockIdx.x >> 3;
  const int p0 = (blockIdx.x & 7) << 7;
  const int o0 = blockIdx.y << 7;
  const int l15 = lane & 15, l4 = lane >> 4;

  float* dstz = dst + (size_t)z * CHW;

  // A staging decode: slot d in [0,1024): row=d>>3, stored-chunk c3 (8-chunk XOR swizzle);
  // logical chunk bit2 selects hi/lo matrix, bits0-1 select k-subchunk.
  int rowA[4], c3A[4];
#pragma unroll
  for (int it = 0; it < 4; ++it) {
    int d = it * 256 + tid;
    rowA[it] = d >> 3;
    c3A[it] = (d & 7) ^ (rowA[it] & 7);
  }
  // B staging decode: slot d in [0,512): row=d>>2, stored-chunk d&3, logical k8 = (d&3)^((row>>1)&3)
  int rowB[2], k8B[2];
#pragma unroll
  for (int it = 0; it < 2; ++it) {
    int d = it * 256 + tid;
    rowB[it] = d >> 2;
    k8B[it] = (d & 3) ^ ((rowB[it] >> 1) & 3);
  }

  f32x4 racc[4][4];
#pragma unroll
  for (int m = 0; m < 4; ++m)
#pragma unroll
    for (int n = 0; n < 4; ++n) racc[m][n] = (f32x4){0.f, 0.f, 0.f, 0.f};

  for (int t = 0; t < nterms; ++t) {
    const int wsel = wselBase + z * 4 + t;
    const u16* aptr[4];
    const u16* bptr[2];
#pragma unroll
    for (int it = 0; it < 4; ++it) {
      int c3 = c3A[it];
      const u16* wb = (c3 & 4) ? Wlo : Whi;
      aptr[it] = wb + ((size_t)wsel * CDIM + o0 + rowA[it]) * CDIM + (c3 & 3) * 8;
    }
#pragma unroll
    for (int it = 0; it < 2; ++it) {
      int srow = sigma_fn(mode, z, t, p0 + rowB[it]);
      bptr[it] = Bx + ((size_t)b * NP + srow) * CDIM + k8B[it] * 8;
    }
    f32x4 acc[4][4];
#pragma unroll
    for (int m = 0; m < 4; ++m)
#pragma unroll
      for (int n = 0; n < 4; ++n) acc[m][n] = (f32x4){0.f, 0.f, 0.f, 0.f};

    for (int k0 = 0; k0 < CDIM; k0 += 32) {
      __syncthreads();  // prior ds_reads done before overwrite
#pragma unroll
      for (int it = 0; it < 4; ++it)
        gload_lds16(aptr[it] + k0, &lds[(size_t)(it * 256 + (w << 6)) * 8]);
#pragma unroll
      for (int it = 0; it < 2; ++it)
        gload_lds16(bptr[it] + k0, &lds[8192 + (size_t)(it * 256 + (w << 6)) * 8]);
      __syncthreads();  // drains vmcnt(0) before barrier

      half8 ah[4], al[4], bh[4];
#pragma unroll
      for (int m = 0; m < 4; ++m) {
        int row = wr * 64 + m * 16 + l15;
        ah[m] = *(const half8*)&lds[(row * 8 + (l4 ^ (row & 7))) * 8];
        al[m] = *(const half8*)&lds[(row * 8 + ((4 + l4) ^ (row & 7))) * 8];
      }
#pragma unroll
      for (int n = 0; n < 4; ++n) {
        int row = wc * 64 + n * 16 + l15;
        int sc = l4 ^ ((row >> 1) & 3);
        bh[n] = *(const half8*)&lds[8192 + row * 32 + sc * 8];
      }
#pragma unroll
      for (int m = 0; m < 4; ++m)
#pragma unroll
        for (int n = 0; n < 4; ++n) {
          acc[m][n] = __builtin_amdgcn_mfma_f32_16x16x32_f16(ah[m], bh[n], acc[m][n], 0, 0, 0);
          acc[m][n] = __builtin_amdgcn_mfma_f32_16x16x32_f16(al[m], bh[n], acc[m][n], 0, 0, 0);
        }
    }
    // relu(term + bias) accumulation
#pragma unroll
    for (int m = 0; m < 4; ++m) {
      float4 bv = *(const float4*)&bias[wsel * CDIM + o0 + wr * 64 + m * 16 + l4 * 4];
      float bvf[4] = {bv.x, bv.y, bv.z, bv.w};
#pragma unroll
      for (int n = 0; n < 4; ++n)
#pragma unroll
        for (int r = 0; r < 4; ++r) racc[m][n][r] += fmaxf(0.f, acc[m][n][r] + bvf[r]);
    }
  }
  // C write: row = o0+wr*64+m*16+l4*4+r, col = p0+wc*64+n*16+l15
#pragma unroll
  for (int m = 0; m < 4; ++m) {
    int rowb = o0 + wr * 64 + m * 16 + l4 * 4;
#pragma unroll
    for (int n = 0; n < 4; ++n) {
      int col = p0 + wc * 64 + n * 16 + l15;
      float* dp = dstz + ((size_t)b * CDIM + rowb) * NP + col;
#pragma unroll
      for (int r = 0; r < 4; ++r) dp[(size_t)r * NP] = racc[m][n][r];
    }
  }
}

// ---------------- per-(b,c) 32x32 attention, fp32, fused transposed-f16 output ----------------
// block = 4 consecutive (b,c) pairs (same b since 4 | 768); writes aoT f16 [b][p][c0..c0+3]
__global__ __launch_bounds__(256) void attn_f_k(const float* __restrict__ hs, u16* __restrict__ aoT) {
  __shared__ float q[4][1056];   // pitch 33
  __shared__ float kk[4][1056];
  const int tid = threadIdx.x, w = tid >> 6, lane = tid & 63;
  const int pair0 = blockIdx.x * 4;
  const int b = pair0 / CDIM;
  const int c0 = pair0 % CDIM;
#pragma unroll
  for (int it = 0; it < 8; ++it) {
    int d4 = it * 256 + tid;
    int pr = d4 >> 9;
    int mat = (d4 >> 8) & 1;
    int off4 = d4 & 255;
    float4 v = *(const float4*)&hs[(size_t)mat * CHW + (size_t)(pair0 + pr) * NP + off4 * 4];
    float* dl = mat ? kk[pr] : q[pr];
    int off = off4 * 4;
    int base = (off >> 5) * 33 + (off & 31);
    dl[base] = v.x; dl[base + 1] = v.y; dl[base + 2] = v.z; dl[base + 3] = v.w;
  }
  __syncthreads();
  const int i = lane & 31, half = lane >> 5, jb = half * 16;
  const float* Q = q[w];
  const float* K = kk[w];
  float qr[32];
#pragma unroll
  for (int tt = 0; tt < 32; ++tt) qr[tt] = Q[i * 33 + tt];
  float a[16];
#pragma unroll
  for (int j = 0; j < 16; ++j) {
    float s = 0.f;
#pragma unroll
    for (int tt = 0; tt < 32; ++tt) s = fmaf(qr[tt], K[tt * 33 + jb + j], s);
    a[j] = s;
  }
  float mx = a[0];
#pragma unroll
  for (int j = 1; j < 16; ++j) mx = fmaxf(mx, a[j]);
  mx = fmaxf(mx, __shfl_xor(mx, 32));
  float ssum = 0.f;
#pragma unroll
  for (int j = 0; j < 16; ++j) { a[j] = expf(a[j] - mx); ssum += a[j]; }
  ssum += __shfl_xor(ssum, 32);
  float inv = 1.f / ssum;
#pragma unroll
  for (int j = 0; j < 16; ++j) a[j] *= inv;
  // out[i][h] = sum_j p[i][j] * v[j][h]; v == q buffer. Stage result into kk (K dead).
#pragma unroll
  for (int h = 0; h < 32; ++h) {
    float o = 0.f;
#pragma unroll
    for (int j = 0; j < 16; ++j) o = fmaf(a[j], Q[(jb + j) * 33 + h], o);
    o += __shfl_xor(o, 32);
    if (half == (h >> 4)) kk[w][i * 33 + h] = o;
  }
  __syncthreads();
  // fused transpose: aoT[b][p][c0+pr] = f16(out[pr][p]); p = i*32+h
#pragma unroll
  for (int it = 0; it < 4; ++it) {
    int p = it * 256 + tid;
    int base = (p >> 5) * 33 + (p & 31);
    ushort4 v;
    v.x = f16bits(kk[0][base]);
    v.y = f16bits(kk[1][base]);
    v.z = f16bits(kk[2][base]);
    v.w = f16bits(kk[3][base]);
    *(ushort4*)&aoT[((size_t)b * NP + p) * CDIM + c0] = v;
  }
}

extern "C" void kernel_launch(void* const* d_in, const int* in_sizes, int n_in,
                              void* d_out, int out_size, void* d_ws, size_t ws_size,
                              hipStream_t stream) {
  (void)in_sizes; (void)n_in; (void)out_size; (void)ws_size;
  const float* x = (const float*)d_in[0];
  const float* Ws = (const float*)d_in[1];
  const float* bs = (const float*)d_in[2];
  float* out = (float*)d_out;
  char* ws = (char*)d_ws;

  u16* XT  = (u16*)(ws + XT_OFF);
  float* hs = (float*)(ws + HS_OFF);
  u16* Whi = (u16*)(ws + WHI_OFF);
  u16* Wlo = (u16*)(ws + WLO_OFF);
  u16* aoT = (u16*)(ws + XT_OFF);   // aliases XT (dead after stage-1)

  // 1. split weights: 9*768*768/4 = 1,327,104 float4 -> 5184 blocks * 256
  split_w_k<<<5184, 256, 0, stream>>>(Ws, Whi, Wlo);
  // 2. x [b][c][p] fp32 -> XT f16 [b][p][c]
  transpose_f16_k<<<dim3(32, 24, 32), 256, 0, stream>>>(x, XT);
  // 3. stage-1: hs11 (z=0, W0..3) and hs111 (z=1, W4..7)
  gemm_ms<<<dim3(256, 6, 2), 256, 0, stream>>>(Whi, Wlo, XT, bs, hs, 4, 0, 0);
  // 4. attention per (b,c) + fused transposed f16 output
  attn_f_k<<<6144, 256, 0, stream>>>(hs, aoT);
  // 5. final conv: relu(W8 @ attout + b8) -> d_out
  gemm_ms<<<dim3(256, 6, 1), 256, 0, stream>>>(Whi, Wlo, aoT, bs, out, 1, 8, 1);
}

// Round 3
// 926.357 us; speedup vs baseline: 1.3928x; 1.0719x over previous
//
#include <hip/hip_runtime.h>
#include <hip/hip_fp16.h>

typedef unsigned short u16;
typedef float f32x4 __attribute__((ext_vector_type(4)));
typedef _Float16 half8 __attribute__((ext_vector_type(8)));
typedef unsigned short u16x4 __attribute__((ext_vector_type(4)));

#define CDIM 768
#define NP 1024
#define NB 32

static constexpr size_t CHW = (size_t)NB * CDIM * NP;  // 25,165,824

// workspace layout (bytes)
static constexpr size_t XT_OFF  = 0;                         // f16 [b][p][c]; later reused as aoT f16
static constexpr size_t HS_OFF  = CHW * 2;                   // fp32 hs11, hs111 (2*CHW*4)
static constexpr size_t WHI_OFF = HS_OFF + CHW * 8;          // f16 hi
static constexpr size_t WLO_OFF = WHI_OFF + (size_t)9 * CDIM * CDIM * 2;

__device__ __forceinline__ u16 f16bits(float f) {
  return __half_as_ushort(__float2half_rn(f));
}

typedef __attribute__((address_space(1))) void gv_t;
typedef __attribute__((address_space(3))) void lv_t;
__device__ __forceinline__ void gload_lds16(const void* g, void* l) {
  __builtin_amdgcn_global_load_lds((gv_t*)g, (lv_t*)l, 16, 0, 0);
}

// ---------------- split W (fp32 -> f16 hi + f16 lo) ----------------
__global__ __launch_bounds__(256) void split_w_k(const float* __restrict__ W,
                                                 u16* __restrict__ hi, u16* __restrict__ lo) {
  int i = blockIdx.x * 256 + threadIdx.x;
  float4 v = ((const float4*)W)[i];
  float f[4] = {v.x, v.y, v.z, v.w};
  u16 hh[4], ll[4];
#pragma unroll
  for (int e = 0; e < 4; ++e) {
    __half h = __float2half_rn(f[e]);
    hh[e] = __half_as_ushort(h);
    ll[e] = f16bits(f[e] - __half2float(h));
  }
  u16x4 h4 = {hh[0], hh[1], hh[2], hh[3]};
  u16x4 l4v = {ll[0], ll[1], ll[2], ll[3]};
  ((u16x4*)hi)[i] = h4;
  ((u16x4*)lo)[i] = l4v;
}

// ---------------- transpose + f16 cast: src fp32 [b][c][p] -> dst f16 [b][p][c] ----------------
__global__ __launch_bounds__(256) void transpose_f16_k(const float* __restrict__ src,
                                                       u16* __restrict__ dxt) {
  __shared__ float tle[32][33];
  const int b = blockIdx.z, c0 = blockIdx.y * 32, p0 = blockIdx.x * 32;
  const int tid = threadIdx.x;
  const int lr = tid >> 5, lc = tid & 31;
  const float* s = src + ((size_t)b * CDIM + c0) * NP + p0;
#pragma unroll
  for (int it = 0; it < 4; ++it) {
    int c = it * 8 + lr;
    tle[c][lc] = s[(size_t)c * NP + lc];
  }
  __syncthreads();
#pragma unroll
  for (int it = 0; it < 4; ++it) {
    int p = it * 8 + lr;
    float v = tle[lc][p];
    size_t off = ((size_t)b * NP + p0 + p) * CDIM + c0 + lc;
    dxt[off] = f16bits(v);
  }
}

// ---------------- spatial permutations ----------------
__device__ __forceinline__ int sigma_fn(int mode, int z, int t, int p) {
  if (t == 0 || mode == 1) return p;
  int i = p >> 5, j = p & 31;
  if (z == 0) {
    if (t == 1) return (j << 5) | (31 - i);
    if (t == 2) return ((31 - i) << 5) | (31 - j);
    return ((31 - j) << 5) | i;
  } else {
    int ib = i & 16, jb = j & 16, il = i & 15, jl = j & 15;
    if (t == 1) return ((ib | jl) << 5) | (jb | (15 - il));
    if (t == 2) return ((ib | (15 - il)) << 5) | (jb | (15 - jl));
    return ((ib | (15 - jl)) << 5) | (jb | il);
  }
}

// ---------------- pipelined multi-term 2x-f16-split GEMM ----------------
// Tile 128(o) x 256(p), BK=32 channels, 512 threads (8 waves, 2M x 4N),
// 3 LDS buffers x 32KB, counted vmcnt(4), depth-2 prefetch, 1 barrier/step.
// dst[z][b][o][p] = sum_t relu( (Whi+Wlo)[wsel] @ Xf16[:, sigma(p)] + bias )
__global__ __launch_bounds__(512, 2) void gemm_p(
    const u16* __restrict__ Whi, const u16* __restrict__ Wlo,
    const u16* __restrict__ Bx,
    const float* __restrict__ bias, float* __restrict__ dst,
    int nterms, int wselBase, int mode) {
  extern __shared__ u16 lds[];  // 3 x 16384 u16; per buf: A [0,8192), B [8192,16384)
  const int tid = threadIdx.x;
  const int lane = tid & 63;
  const int w = tid >> 6;
  const int wr = w >> 2, wc = w & 3;
  const int z = blockIdx.z;
  const int b = blockIdx.x >> 2;
  const int p0 = (blockIdx.x & 3) << 8;
  const int o0 = blockIdx.y << 7;
  const int l15 = lane & 15, l4 = lane >> 4;

  float* dstz = dst + (size_t)z * CHW;
  const int NSTEP = nterms * 24;

  // A staging: slots d in [0,1024): row=d>>3 (0..127), chunk c3=(d&7)^(row&7);
  //   c3 bit2 -> hi/lo matrix, bits0-1 -> k-subchunk of 8 u16.
  // B staging: slots d in [0,1024): row=d>>2 (0..255), stored chunk d&3,
  //   logical k8 = (d&3)^((row>>1)&3).
  auto stage = [&](int s, int buf) {
    int term = (s * 2731) >> 16;           // s/24 for s<96
    int k0 = (s - term * 24) * 32;
    int wsel = wselBase + z * 4 + term;
    u16* lbase = &lds[(size_t)buf * 16384];
#pragma unroll
    for (int it = 0; it < 2; ++it) {
      int d = it * 512 + tid;
      int row = d >> 3, c3 = (d & 7) ^ (row & 7);
      const u16* src = ((c3 & 4) ? Wlo : Whi) +
                       ((size_t)wsel * CDIM + o0 + row) * CDIM + (c3 & 3) * 8 + k0;
      gload_lds16(src, lbase + (size_t)d * 8);
    }
#pragma unroll
    for (int it = 0; it < 2; ++it) {
      int d = it * 512 + tid;
      int row = d >> 2, k8 = (d & 3) ^ ((row >> 1) & 3);
      int srow = sigma_fn(mode, z, term, p0 + row);
      const u16* src = Bx + ((size_t)b * NP + srow) * CDIM + k8 * 8 + k0;
      gload_lds16(src, lbase + 8192 + (size_t)d * 8);
    }
  };

  f32x4 acc[4][4], racc[4][4];
#pragma unroll
  for (int m = 0; m < 4; ++m)
#pragma unroll
    for (int n = 0; n < 4; ++n) {
      acc[m][n] = (f32x4){0.f, 0.f, 0.f, 0.f};
      racc[m][n] = (f32x4){0.f, 0.f, 0.f, 0.f};
    }
  float4 bvm[4];

  stage(0, 0);
  stage(1, 1);
  int cur = 0;

  for (int s = 0; s < NSTEP; ++s) {
    // wait for buffer `cur`'s 4 loads (mine); keep next stage's 4 in flight
    if (s + 1 < NSTEP) {
      asm volatile("s_waitcnt vmcnt(4)" ::: "memory");
    } else {
      asm volatile("s_waitcnt vmcnt(0)" ::: "memory");
    }
    __builtin_amdgcn_s_barrier();        // all waves' stage(s) landed
    asm volatile("" ::: "memory");       // no LDS reads hoisted above barrier

    int term = (s * 2731) >> 16;
    int kk = s - term * 24;
    if (kk == 0) {
      int wsel = wselBase + z * 4 + term;
#pragma unroll
      for (int m = 0; m < 4; ++m)
        bvm[m] = *(const float4*)&bias[wsel * CDIM + o0 + wr * 64 + m * 16 + l4 * 4];
    }
    {
      int nb = cur + 2; if (nb >= 3) nb -= 3;
      if (s + 2 < NSTEP) stage(s + 2, nb);
    }

    const u16* la = &lds[(size_t)cur * 16384];
    const u16* lb = la + 8192;
    half8 ah[4], al[4], bh[4];
#pragma unroll
    for (int m = 0; m < 4; ++m) {
      int row = wr * 64 + m * 16 + l15;
      ah[m] = *(const half8*)&la[(row * 8 + (l4 ^ (row & 7))) * 8];
      al[m] = *(const half8*)&la[(row * 8 + ((4 + l4) ^ (row & 7))) * 8];
    }
#pragma unroll
    for (int n = 0; n < 4; ++n) {
      int row = wc * 64 + n * 16 + l15;
      bh[n] = *(const half8*)&lb[row * 32 + (l4 ^ ((row >> 1) & 3)) * 8];
    }
    __builtin_amdgcn_s_setprio(1);
#pragma unroll
    for (int m = 0; m < 4; ++m)
#pragma unroll
      for (int n = 0; n < 4; ++n) {
        acc[m][n] = __builtin_amdgcn_mfma_f32_16x16x32_f16(ah[m], bh[n], acc[m][n], 0, 0, 0);
        acc[m][n] = __builtin_amdgcn_mfma_f32_16x16x32_f16(al[m], bh[n], acc[m][n], 0, 0, 0);
      }
    __builtin_amdgcn_s_setprio(0);

    if (kk == 23) {  // term boundary: relu(acc + bias) -> racc, reset acc
#pragma unroll
      for (int m = 0; m < 4; ++m) {
        float bvf[4] = {bvm[m].x, bvm[m].y, bvm[m].z, bvm[m].w};
#pragma unroll
        for (int n = 0; n < 4; ++n)
#pragma unroll
          for (int r = 0; r < 4; ++r) {
            racc[m][n][r] += fmaxf(0.f, acc[m][n][r] + bvf[r]);
            acc[m][n][r] = 0.f;
          }
      }
    }
    cur = cur == 2 ? 0 : cur + 1;
  }

  // C write: row = o0+wr*64+m*16+l4*4+r, col = p0+wc*64+n*16+l15
#pragma unroll
  for (int m = 0; m < 4; ++m) {
    int rowb = o0 + wr * 64 + m * 16 + l4 * 4;
#pragma unroll
    for (int n = 0; n < 4; ++n) {
      int col = p0 + wc * 64 + n * 16 + l15;
      float* dp = dstz + ((size_t)b * CDIM + rowb) * NP + col;
#pragma unroll
      for (int r = 0; r < 4; ++r) dp[(size_t)r * NP] = racc[m][n][r];
    }
  }
}

// ---------------- per-(b,c) 32x32 attention, fp32, fused transposed-f16 output ----------------
__global__ __launch_bounds__(256) void attn_f_k(const float* __restrict__ hs, u16* __restrict__ aoT) {
  __shared__ float q[4][1056];   // pitch 33
  __shared__ float kk[4][1056];
  const int tid = threadIdx.x, w = tid >> 6, lane = tid & 63;
  const int pair0 = blockIdx.x * 4;
  const int b = pair0 / CDIM;
  const int c0 = pair0 % CDIM;
#pragma unroll
  for (int it = 0; it < 8; ++it) {
    int d4 = it * 256 + tid;
    int pr = d4 >> 9;
    int mat = (d4 >> 8) & 1;
    int off4 = d4 & 255;
    float4 v = *(const float4*)&hs[(size_t)mat * CHW + (size_t)(pair0 + pr) * NP + off4 * 4];
    float* dl = mat ? kk[pr] : q[pr];
    int off = off4 * 4;
    int base = (off >> 5) * 33 + (off & 31);
    dl[base] = v.x; dl[base + 1] = v.y; dl[base + 2] = v.z; dl[base + 3] = v.w;
  }
  __syncthreads();
  const int i = lane & 31, half = lane >> 5, jb = half * 16;
  const float* Q = q[w];
  const float* K = kk[w];
  float qr[32];
#pragma unroll
  for (int tt = 0; tt < 32; ++tt) qr[tt] = Q[i * 33 + tt];
  float a[16];
#pragma unroll
  for (int j = 0; j < 16; ++j) {
    float s = 0.f;
#pragma unroll
    for (int tt = 0; tt < 32; ++tt) s = fmaf(qr[tt], K[tt * 33 + jb + j], s);
    a[j] = s;
  }
  float mx = a[0];
#pragma unroll
  for (int j = 1; j < 16; ++j) mx = fmaxf(mx, a[j]);
  mx = fmaxf(mx, __shfl_xor(mx, 32));
  float ssum = 0.f;
#pragma unroll
  for (int j = 0; j < 16; ++j) { a[j] = expf(a[j] - mx); ssum += a[j]; }
  ssum += __shfl_xor(ssum, 32);
  float inv = 1.f / ssum;
#pragma unroll
  for (int j = 0; j < 16; ++j) a[j] *= inv;
#pragma unroll
  for (int h = 0; h < 32; ++h) {
    float o = 0.f;
#pragma unroll
    for (int j = 0; j < 16; ++j) o = fmaf(a[j], Q[(jb + j) * 33 + h], o);
    o += __shfl_xor(o, 32);
    if (half == (h >> 4)) kk[w][i * 33 + h] = o;
  }
  __syncthreads();
#pragma unroll
  for (int it = 0; it < 4; ++it) {
    int p = it * 256 + tid;
    int base = (p >> 5) * 33 + (p & 31);
    ushort4 v;
    v.x = f16bits(kk[0][base]);
    v.y = f16bits(kk[1][base]);
    v.z = f16bits(kk[2][base]);
    v.w = f16bits(kk[3][base]);
    *(ushort4*)&aoT[((size_t)b * NP + p) * CDIM + c0] = v;
  }
}

extern "C" void kernel_launch(void* const* d_in, const int* in_sizes, int n_in,
                              void* d_out, int out_size, void* d_ws, size_t ws_size,
                              hipStream_t stream) {
  (void)in_sizes; (void)n_in; (void)out_size; (void)ws_size;
  const float* x = (const float*)d_in[0];
  const float* Ws = (const float*)d_in[1];
  const float* bs = (const float*)d_in[2];
  float* out = (float*)d_out;
  char* ws = (char*)d_ws;

  u16* XT  = (u16*)(ws + XT_OFF);
  float* hs = (float*)(ws + HS_OFF);
  u16* Whi = (u16*)(ws + WHI_OFF);
  u16* Wlo = (u16*)(ws + WLO_OFF);
  u16* aoT = (u16*)(ws + XT_OFF);   // aliases XT (dead after stage-1)

  split_w_k<<<5184, 256, 0, stream>>>(Ws, Whi, Wlo);
  transpose_f16_k<<<dim3(32, 24, 32), 256, 0, stream>>>(x, XT);
  // stage-1: hs11 (z=0, W0..3) and hs111 (z=1, W4..7); 128x256 tiles
  gemm_p<<<dim3(128, 6, 2), 512, 98304, stream>>>(Whi, Wlo, XT, bs, hs, 4, 0, 0);
  attn_f_k<<<6144, 256, 0, stream>>>(hs, aoT);
  // final conv: relu(W8 @ attout + b8) -> d_out
  gemm_p<<<dim3(128, 6, 1), 512, 98304, stream>>>(Whi, Wlo, aoT, bs, out, 1, 8, 1);
}